// Round 1
// baseline (88.807 us; speedup 1.0000x reference)
//
#include <hip/hip_runtime.h>
#include <hip/hip_bf16.h>

// Problem constants
#define T_ 8192
#define H_ 64
#define X_ 128
#define C_ 128   // number of chunks
#define L_ 64    // chunk length (C_*L_ == T_)
#define TB 8     // t-rows per block in the b-projection kernel

// Broadcast a float from lane `src` (compile-time constant) to all lanes.
__device__ __forceinline__ float bcast(float v, int src) {
    return __int_as_float(__builtin_amdgcn_readlane(__float_as_int(v), src));
}

// One recurrence step: newh[i] = sum_j arow[j]*h[j] + b_i, with h lane-distributed
// (lane j holds h[j]) and arow[] held in registers (compile-time indexed only).
__device__ __forceinline__ float lru_step(const float* arow, float h, float b_i) {
    float a0 = b_i, a1 = 0.f, a2 = 0.f, a3 = 0.f;
#pragma unroll
    for (int j = 0; j < 16; ++j) {
        a0 = fmaf(arow[j],      bcast(h, j),      a0);
        a1 = fmaf(arow[j + 16], bcast(h, j + 16), a1);
        a2 = fmaf(arow[j + 32], bcast(h, j + 32), a2);
        a3 = fmaf(arow[j + 48], bcast(h, j + 48), a3);
    }
    return (a0 + a1) + (a2 + a3);
}

// Build row `lane` of A = 0.9*I + 0.1*A_raw into registers.
__device__ __forceinline__ void load_arow_A(const float* __restrict__ A_raw,
                                            int lane, float* arow) {
    const float4* a4 = (const float4*)(A_raw + lane * 64);
#pragma unroll
    for (int q = 0; q < 16; ++q) {
        float4 t4 = a4[q];
        arow[4 * q + 0] = 0.1f * t4.x;
        arow[4 * q + 1] = 0.1f * t4.y;
        arow[4 * q + 2] = 0.1f * t4.z;
        arow[4 * q + 3] = 0.1f * t4.w;
    }
#pragma unroll
    for (int q = 0; q < 64; ++q) arow[q] += (q == lane) ? 0.9f : 0.0f;
}

// K1: b[t][h] = sum_x x[t][x] * B[h][x] + c[h]  -> written into d_out
__global__ __launch_bounds__(256) void k_bproj(const float* __restrict__ x,
                                               const float* __restrict__ B,
                                               const float* __restrict__ c,
                                               float* __restrict__ b_out) {
    __shared__ float Bs[H_][X_ + 1];  // +1 pad: bank = (h+x)%32 -> 2 lanes/bank (free)
    __shared__ float xs[TB][X_];
    const int tid = threadIdx.x;
    const int t0 = blockIdx.x * TB;

    for (int idx = tid; idx < H_ * X_; idx += 256) {
        Bs[idx >> 7][idx & 127] = B[idx];
    }
    for (int idx = tid; idx < TB * X_; idx += 256) {
        xs[idx >> 7][idx & 127] = x[t0 * X_ + idx];
    }
    __syncthreads();

    const int h  = tid & 63;
    const int tp = tid >> 6;  // 0..3 ; handles rows tp and tp+4
    const float cc = c[h];
    float acc0 = cc, acc1 = cc;
#pragma unroll 4
    for (int xx = 0; xx < X_; ++xx) {
        const float bv = Bs[h][xx];
        acc0 = fmaf(xs[tp][xx],     bv, acc0);
        acc1 = fmaf(xs[tp + 4][xx], bv, acc1);
    }
    b_out[(size_t)(t0 + tp) * H_ + h]     = acc0;
    b_out[(size_t)(t0 + tp + 4) * H_ + h] = acc1;
}

// K2: blocks 0..C_-1: chunk-local recurrence from zero state -> v[c][:]
//     blocks C_..C_+H_-1: column (wid-C_) of A^L via recurrence on e_col -> AL
__global__ __launch_bounds__(64) void k_phase1(const float* __restrict__ A_raw,
                                               const float* __restrict__ b,
                                               float* __restrict__ v,
                                               float* __restrict__ AL) {
    const int lane = threadIdx.x;
    const int wid  = blockIdx.x;
    float arow[64];
    load_arow_A(A_raw, lane, arow);

    if (wid < C_) {
        const float* bc = b + (size_t)wid * L_ * H_;
        float h = 0.f;
#pragma unroll 2
        for (int t = 0; t < L_; ++t) {
            const float bi = bc[(size_t)t * H_ + lane];
            h = lru_step(arow, h, bi);
        }
        v[wid * H_ + lane] = h;
    } else {
        const int col = wid - C_;
        float h = (lane == col) ? 1.f : 0.f;
#pragma unroll 2
        for (int t = 0; t < L_; ++t) {
            h = lru_step(arow, h, 0.f);
        }
        AL[lane * 64 + col] = h;  // row-major A^L
    }
}

// K3: serial scan over chunks with A^L: hstart[c] = h_end[c-1] (hstart[0] = h0)
__global__ __launch_bounds__(64) void k_phase2(const float* __restrict__ AL,
                                               const float* __restrict__ h0,
                                               const float* __restrict__ v,
                                               float* __restrict__ hstart) {
    const int lane = threadIdx.x;
    float arow[64];
    const float4* a4 = (const float4*)(AL + lane * 64);
#pragma unroll
    for (int q = 0; q < 16; ++q) {
        float4 t4 = a4[q];
        arow[4 * q + 0] = t4.x;
        arow[4 * q + 1] = t4.y;
        arow[4 * q + 2] = t4.z;
        arow[4 * q + 3] = t4.w;
    }
    float h = h0[lane];
#pragma unroll 2
    for (int c = 0; c < C_; ++c) {
        hstart[c * H_ + lane] = h;
        const float vi = v[c * H_ + lane];
        h = lru_step(arow, h, vi);
    }
}

// K4: replay each chunk from hstart, overwriting b rows in d_out with h rows.
__global__ __launch_bounds__(64) void k_phase3(const float* __restrict__ A_raw,
                                               const float* __restrict__ hstart,
                                               float* __restrict__ out) {
    const int lane = threadIdx.x;
    const int cid  = blockIdx.x;
    float arow[64];
    load_arow_A(A_raw, lane, arow);

    float h = hstart[cid * H_ + lane];
    float* oc = out + (size_t)cid * L_ * H_;
#pragma unroll 2
    for (int t = 0; t < L_; ++t) {
        const float bi = oc[(size_t)t * H_ + lane];
        h = lru_step(arow, h, bi);
        oc[(size_t)t * H_ + lane] = h;
    }
}

extern "C" void kernel_launch(void* const* d_in, const int* in_sizes, int n_in,
                              void* d_out, int out_size, void* d_ws, size_t ws_size,
                              hipStream_t stream) {
    const float* x     = (const float*)d_in[0];  // [T, X]
    const float* h0    = (const float*)d_in[1];  // [H]
    const float* A_raw = (const float*)d_in[2];  // [H, H]
    const float* B     = (const float*)d_in[3];  // [H, X]
    const float* c     = (const float*)d_in[4];  // [H]
    float* out = (float*)d_out;                  // [T, H]; reused as b storage
    float* ws  = (float*)d_ws;

    float* AL     = ws;                 // 4096 floats
    float* v      = ws + 4096;          // C_*H_ = 8192 floats
    float* hstart = ws + 4096 + 8192;   // C_*H_ = 8192 floats

    k_bproj <<<T_ / TB, 256, 0, stream>>>(x, B, c, out);
    k_phase1<<<C_ + H_, 64, 0, stream>>>(A_raw, out, v, AL);
    k_phase2<<<1,       64, 0, stream>>>(AL, h0, v, hstart);
    k_phase3<<<C_,      64, 0, stream>>>(A_raw, hstart, out);
}